// Round 5
// baseline (688.497 us; speedup 1.0000x reference)
//
#include <hip/hip_runtime.h>
#include <hip/hip_bf16.h>
#include <stdint.h>

#define NN 100000
#define NE 1600000
#define FIN 100
#define HID 128
#define CLS 47

typedef __attribute__((ext_vector_type(8))) short bf16x8;
typedef __attribute__((ext_vector_type(4))) float f32x4;

#define AS1(p) ((const __attribute__((address_space(1))) void*)(p))
#define AS3(p) ((__attribute__((address_space(3))) void*)(p))

__device__ __forceinline__ uint16_t f2bf(float f) {
  union { float f; uint32_t u; } v; v.f = f;
  uint32_t r = v.u + 0x7fffu + ((v.u >> 16) & 1u);
  return (uint16_t)(r >> 16);
}

// ---- weight packing: B_l[j][k] (128 x 256) bf16; k<128 -> W_rel, k>=128 -> W_root (layer1 zero-padded)
__global__ void pack_weights(const float* __restrict__ W1r, const float* __restrict__ W1o,
                             const float* __restrict__ W2r, const float* __restrict__ W2o,
                             const float* __restrict__ W3r, const float* __restrict__ W3o,
                             uint16_t* __restrict__ B1, uint16_t* __restrict__ B2, uint16_t* __restrict__ B3) {
  int idx = blockIdx.x * 256 + threadIdx.x;      // < 3*128*256
  int l = idx >> 15;
  int rem = idx & 32767;
  int j = rem >> 8;
  int k = rem & 255;
  if (l == 0) {
    uint16_t v = 0;
    if (k < FIN) v = f2bf(W1r[j*FIN + k]);
    else if (k >= 128 && k < 128 + FIN) v = f2bf(W1o[j*FIN + (k - 128)]);
    B1[j*256 + k] = v;
  } else if (l == 1) {
    B2[j*256 + k] = (k < 128) ? f2bf(W2r[j*128 + k]) : f2bf(W2o[j*128 + (k - 128)]);
  } else {
    B3[j*256 + k] = (k < 128) ? f2bf(W3r[j*128 + k]) : f2bf(W3o[j*128 + (k - 128)]);
  }
}

// ---- W_lin [47,384] f32 -> Wlb [48,384] bf16 (row 47 zero)
__global__ void pack_wl(const float* __restrict__ Wl, uint16_t* __restrict__ Wlb) {
  int idx = blockIdx.x * 256 + threadIdx.x;      // < 48*384
  int r = idx / 384;
  int c = idx - r * 384;
  Wlb[idx] = (r < CLS) ? f2bf(Wl[r*384 + c]) : (uint16_t)0;
}

// ---- pad+convert x0 [N,100] f32 -> x0p [N,128] bf16 (zeros in cols 100..127); 4 nodes/block
__global__ __launch_bounds__(256) void pad_x0(const float* __restrict__ x0, uint16_t* __restrict__ x0p) {
  int n = blockIdx.x * 4 + (threadIdx.x >> 6);
  int c = 2 * (threadIdx.x & 63);
  uint32_t o = 0;
  if (c < FIN) {
    float2 v = *(const float2*)(x0 + (size_t)n*FIN + c);
    o = ((uint32_t)f2bf(v.y) << 16) | (uint32_t)f2bf(v.x);
  }
  *(uint32_t*)(x0p + (size_t)n*HID + c) = o;
}

// ---- CSR build: 2 edges/thread (12.5k waves = still >=32 waves/CU TLP, 2x ILP)
__global__ void hist_kernel(const int* __restrict__ dst, int* __restrict__ deg) {
  int base = (blockIdx.x * 256 + threadIdx.x) * 2;
  if (base >= NE) return;
  int2 d2 = *(const int2*)(dst + base);
  atomicAdd(&deg[d2.x], 1);
  atomicAdd(&deg[d2.y], 1);
}

__global__ void scan_local(const int* __restrict__ deg, int* __restrict__ outv, int* __restrict__ bsums) {
  __shared__ int sh[256];
  int i = blockIdx.x * 256 + threadIdx.x;
  int v = (i < NN) ? deg[i] : 0;
  sh[threadIdx.x] = v;
  __syncthreads();
  #pragma unroll
  for (int off = 1; off < 256; off <<= 1) {
    int tv = (threadIdx.x >= off) ? sh[threadIdx.x - off] : 0;
    __syncthreads();
    sh[threadIdx.x] += tv;
    __syncthreads();
  }
  if (i < NN) outv[i] = sh[threadIdx.x] - v;      // exclusive
  if (threadIdx.x == 255) bsums[blockIdx.x] = sh[255];
}

__global__ void scan_sums(int* __restrict__ bsums, int nb) {
  __shared__ int sh[512];
  int t = threadIdx.x;
  int v = (t < nb) ? bsums[t] : 0;
  sh[t] = v;
  __syncthreads();
  for (int off = 1; off < 512; off <<= 1) {
    int tv = (t >= off) ? sh[t - off] : 0;
    __syncthreads();
    sh[t] += tv;
    __syncthreads();
  }
  if (t < nb) bsums[t] = sh[t] - v;               // exclusive block offsets
}

__global__ void scan_add(int* __restrict__ row_start, const int* __restrict__ bsums, int* __restrict__ fill) {
  int i = blockIdx.x * 256 + threadIdx.x;
  if (i < NN) {
    int v = row_start[i] + bsums[blockIdx.x];
    row_start[i] = v;
    fill[i] = v;
  } else if (i == NN) {
    row_start[NN] = NE;
  }
}

// edge record: {src byte-offset, weight-bits}; 2 edges/thread (keeps full TLP, 2x ILP)
__global__ void scatter_kernel(const int* __restrict__ src, const int* __restrict__ dst, const float* __restrict__ ew,
                               int* __restrict__ fill, int2* __restrict__ erec) {
  int base = (blockIdx.x * 256 + threadIdx.x) * 2;
  if (base >= NE) return;
  int2 s2 = *(const int2*)(src + base);
  int2 d2 = *(const int2*)(dst + base);
  float2 w2 = *(const float2*)(ew + base);
  int p0 = atomicAdd(&fill[d2.x], 1);
  int p1 = atomicAdd(&fill[d2.y], 1);
  erec[p0] = make_int2(s2.x * (HID * 2), __float_as_int(w2.x));
  erec[p1] = make_int2(s2.y * (HID * 2), __float_as_int(w2.y));
}

// ---- SpMM: agg[n,:] = sum_{e in row n} w_e * x[src_e,:]
// one wave per node, lane = 2 cols. Predicated batches of 16: erec loads are
// wave-uniform (-> SGPR s_loads), so VGPR cost is just the 16 gather results.
// Avg degree 16 => most rows finish in ONE gather round. Clamped waste lanes
// re-hit one L1-resident line with w=0 (bandwidth-free).
__global__ __launch_bounds__(256) void spmm_kernel(const uint16_t* __restrict__ x,
                                                   const int* __restrict__ row_start,
                                                   const int2* __restrict__ erec,
                                                   uint16_t* __restrict__ agg) {
  int n = blockIdx.x * 4 + (threadIdx.x >> 6);
  int l = threadIdx.x & 63;
  int s0 = row_start[n], s1 = row_start[n + 1];
  const char* xb = (const char*)x;
  int loff = 4 * l;
  float a0 = 0.f, a1 = 0.f;
  for (int e = s0; e < s1; e += 16) {
    int2 r[16];
    #pragma unroll
    for (int u = 0; u < 16; ++u) {
      int ee = e + u;
      r[u] = erec[ee < s1 ? ee : s1 - 1];
    }
    uint32_t pair[16];
    #pragma unroll
    for (int u = 0; u < 16; ++u)
      pair[u] = *(const uint32_t*)(xb + (size_t)(uint32_t)r[u].x + loff);
    #pragma unroll
    for (int u = 0; u < 16; ++u) {
      float w = (e + u < s1) ? __int_as_float(r[u].y) : 0.f;
      union { uint32_t u32; float f; } lo, hi;
      lo.u32 = pair[u] << 16; hi.u32 = pair[u] & 0xffff0000u;
      a0 += w * lo.f;
      a1 += w * hi.f;
    }
  }
  uint32_t o = ((uint32_t)f2bf(a1) << 16) | (uint32_t)f2bf(a0);
  *(uint32_t*)(agg + (size_t)n*HID + 2*l) = o;
}

// ---- fused GEMM: out = relu([A1|A2] @ B^T + bias), A1/A2 [N,128] bf16, B [128 x 256] bf16 (j-major), bias f32
__global__ __launch_bounds__(256) void gemm_kernel(const uint16_t* __restrict__ A1, const uint16_t* __restrict__ A2,
                                                   const uint16_t* __restrict__ Bm, const float* __restrict__ bias,
                                                   uint16_t* __restrict__ out) {
  __shared__ uint16_t ldsA[128 * 32];
  __shared__ uint16_t ldsB[128 * 32];
  int t = threadIdx.x;
  int n0 = blockIdx.x * 128;
  int lane = t & 63, wave = t >> 6;
  int wm = (wave >> 1) * 64, wn = (wave & 1) * 64;
  int l15 = lane & 15, quad = lane >> 4;

  f32x4 acc[4][4];
  #pragma unroll
  for (int i = 0; i < 4; ++i)
    #pragma unroll
    for (int j = 0; j < 4; ++j) acc[i][j] = (f32x4){0.f, 0.f, 0.f, 0.f};

  for (int kt = 0; kt < 8; ++kt) {
    int kbase = kt * 32;
    const uint16_t* Asrc = (kbase < 128) ? A1 : A2;
    int klocal = kbase & 127;
    #pragma unroll
    for (int q = 0; q < 2; ++q) {
      int u = t + q * 256;                 // 0..511
      int r = u >> 2;                      // 0..127
      int kg = (u & 3) * 8;
      int rowA = n0 + r; if (rowA >= NN) rowA = NN - 1;
      __builtin_amdgcn_global_load_lds(AS1(Asrc + (size_t)rowA*HID + klocal + kg), AS3(&ldsA[u * 8]), 16, 0, 0);
      __builtin_amdgcn_global_load_lds(AS1(Bm + r*256 + kbase + kg), AS3(&ldsB[u * 8]), 16, 0, 0);
    }
    __syncthreads();
    bf16x8 af[4], bfr[4];
    #pragma unroll
    for (int mi = 0; mi < 4; ++mi) af[mi] = *(const bf16x8*)&ldsA[(wm + mi*16 + l15) * 32 + quad * 8];
    #pragma unroll
    for (int ni = 0; ni < 4; ++ni) bfr[ni] = *(const bf16x8*)&ldsB[(wn + ni*16 + l15) * 32 + quad * 8];
    #pragma unroll
    for (int mi = 0; mi < 4; ++mi)
      #pragma unroll
      for (int ni = 0; ni < 4; ++ni)
        acc[mi][ni] = __builtin_amdgcn_mfma_f32_16x16x32_bf16(af[mi], bfr[ni], acc[mi][ni], 0, 0, 0);
    __syncthreads();
  }

  #pragma unroll
  for (int mi = 0; mi < 4; ++mi) {
    #pragma unroll
    for (int ni = 0; ni < 4; ++ni) {
      int c = wn + ni*16 + l15;
      float bc = bias[c];
      #pragma unroll
      for (int i = 0; i < 4; ++i) {
        int r = n0 + wm + mi*16 + quad*4 + i;
        if (r < NN) {
          float v = acc[mi][ni][i] + bc;
          v = v > 0.f ? v : 0.f;
          out[(size_t)r*HID + c] = f2bf(v);
        }
      }
    }
  }
}

// ---- final: logits = [x1|x2|x3] @ Wlb^T + bl ; log_softmax ; store f32
__global__ __launch_bounds__(256) void final_kernel(const uint16_t* __restrict__ x1, const uint16_t* __restrict__ x2,
                                                    const uint16_t* __restrict__ x3,
                                                    const uint16_t* __restrict__ Wlb, const float* __restrict__ bl,
                                                    float* __restrict__ out) {
  int t = threadIdx.x;
  int lane = t & 63, wave = t >> 6;
  int n0 = blockIdx.x * 64 + wave * 16;
  int l15 = lane & 15, quad = lane >> 4;

  f32x4 acc[3];
  #pragma unroll
  for (int i = 0; i < 3; ++i) acc[i] = (f32x4){0.f, 0.f, 0.f, 0.f};

  int arow = n0 + l15; if (arow >= NN) arow = NN - 1;

  #pragma unroll
  for (int kt = 0; kt < 12; ++kt) {
    const uint16_t* xs = (kt < 4) ? x1 : (kt < 8) ? x2 : x3;
    int klocal = (kt & 3) * 32 + quad * 8;
    bf16x8 af = *(const bf16x8*)(xs + (size_t)arow*HID + klocal);
    int kglob = kt * 32 + quad * 8;
    #pragma unroll
    for (int nt = 0; nt < 3; ++nt) {
      int c = nt*16 + l15;                 // < 48, row 47 of Wlb is zero
      bf16x8 bfr = *(const bf16x8*)(Wlb + (size_t)c*(3*HID) + kglob);
      acc[nt] = __builtin_amdgcn_mfma_f32_16x16x32_bf16(af, bfr, acc[nt], 0, 0, 0);
    }
  }

  float bias[3]; bool valid[3];
  #pragma unroll
  for (int nt = 0; nt < 3; ++nt) {
    int c = nt*16 + l15;
    valid[nt] = (c < CLS);
    bias[nt] = valid[nt] ? bl[c] : 0.f;
  }

  #pragma unroll
  for (int i = 0; i < 4; ++i) {
    int r = n0 + quad*4 + i;
    float v0 = acc[0][i] + bias[0];
    float v1 = acc[1][i] + bias[1];
    float v2 = valid[2] ? (acc[2][i] + bias[2]) : -INFINITY;
    float m = fmaxf(v0, fmaxf(v1, v2));
    #pragma unroll
    for (int off = 8; off >= 1; off >>= 1) m = fmaxf(m, __shfl_xor(m, off, 64));
    float s = __expf(v0 - m) + __expf(v1 - m) + (valid[2] ? __expf(v2 - m) : 0.f);
    #pragma unroll
    for (int off = 8; off >= 1; off >>= 1) s += __shfl_xor(s, off, 64);
    float lse = m + __logf(s);
    if (r < NN) {
      out[(size_t)r*CLS + l15]      = v0 - lse;
      out[(size_t)r*CLS + 16 + l15] = v1 - lse;
      if (valid[2]) out[(size_t)r*CLS + 32 + l15] = v2 - lse;
    }
  }
}

extern "C" void kernel_launch(void* const* d_in, const int* in_sizes, int n_in,
                              void* d_out, int out_size, void* d_ws, size_t ws_size,
                              hipStream_t stream) {
  (void)in_sizes; (void)n_in; (void)out_size; (void)ws_size;
  const float* x0  = (const float*)d_in[0];
  const int*   ei  = (const int*)d_in[1];
  const float* ew  = (const float*)d_in[2];
  const float* W1r = (const float*)d_in[3];
  const float* W1o = (const float*)d_in[4];
  const float* b1  = (const float*)d_in[5];
  const float* W2r = (const float*)d_in[6];
  const float* W2o = (const float*)d_in[7];
  const float* b2  = (const float*)d_in[8];
  const float* W3r = (const float*)d_in[9];
  const float* W3o = (const float*)d_in[10];
  const float* b3  = (const float*)d_in[11];
  const float* Wl  = (const float*)d_in[12];
  const float* bl  = (const float*)d_in[13];
  const int* src = ei;
  const int* dst = ei + NE;

  char* ws = (char*)d_ws;
  size_t off = 0;
  auto alloc = [&](size_t bytes) -> void* {
    void* p = ws + off;
    off += (bytes + 255) & ~(size_t)255;
    return p;
  };
  uint16_t* x0p = (uint16_t*)alloc((size_t)NN * HID * 2);   // also reused as xb2
  uint16_t* xb1 = (uint16_t*)alloc((size_t)NN * HID * 2);
  uint16_t* xb3 = (uint16_t*)alloc((size_t)NN * HID * 2);
  uint16_t* agg = (uint16_t*)alloc((size_t)NN * HID * 2);
  int2*   erec      = (int2*)alloc((size_t)NE * 8);
  int*    row_start = (int*)alloc((size_t)(NN + 1) * 4);
  int*    fill      = (int*)alloc((size_t)NN * 4);          // also used as deg
  int*    bsums     = (int*)alloc(512 * 4);
  uint16_t* B1 = (uint16_t*)alloc(128 * 256 * 2);
  uint16_t* B2 = (uint16_t*)alloc(128 * 256 * 2);
  uint16_t* B3 = (uint16_t*)alloc(128 * 256 * 2);
  uint16_t* Wlb = (uint16_t*)alloc(48 * 384 * 2);
  uint16_t* xb2 = x0p;   // alias: x0p dead after layer-1 GEMM

  const int NB = (NN + 255) / 256;        // 391
  const int EB2 = (NE / 2 + 255) / 256;   // 3125

  hipMemsetAsync(fill, 0, (size_t)NN * 4, stream);
  pack_weights<<<384, 256, 0, stream>>>(W1r, W1o, W2r, W2o, W3r, W3o, B1, B2, B3);
  pack_wl<<<72, 256, 0, stream>>>(Wl, Wlb);
  pad_x0<<<NN / 4, 256, 0, stream>>>(x0, x0p);
  hist_kernel<<<EB2, 256, 0, stream>>>(dst, fill);
  scan_local<<<NB, 256, 0, stream>>>(fill, row_start, bsums);
  scan_sums<<<1, 512, 0, stream>>>(bsums, NB);
  scan_add<<<NB, 256, 0, stream>>>(row_start, bsums, fill);
  scatter_kernel<<<EB2, 256, 0, stream>>>(src, dst, ew, fill, erec);

  spmm_kernel<<<NN / 4, 256, 0, stream>>>(x0p, row_start, erec, agg);
  gemm_kernel<<<(NN + 127) / 128, 256, 0, stream>>>(agg, x0p, B1, b1, xb1);
  spmm_kernel<<<NN / 4, 256, 0, stream>>>(xb1, row_start, erec, agg);
  gemm_kernel<<<(NN + 127) / 128, 256, 0, stream>>>(agg, xb1, B2, b2, xb2);
  spmm_kernel<<<NN / 4, 256, 0, stream>>>(xb2, row_start, erec, agg);
  gemm_kernel<<<(NN + 127) / 128, 256, 0, stream>>>(agg, xb2, B3, b3, xb3);

  final_kernel<<<(NN + 63) / 64, 256, 0, stream>>>(xb1, xb2, xb3, Wlb, bl, (float*)d_out);
}

// Round 6
// 533.218 us; speedup vs baseline: 1.2912x; 1.2912x over previous
//
#include <hip/hip_runtime.h>
#include <hip/hip_bf16.h>
#include <stdint.h>

#define NN 100000
#define NE 1600000
#define FIN 100
#define HID 128
#define CLS 47
#define NBUK 391            // ceil(NN/256) buckets of 256 nodes

typedef __attribute__((ext_vector_type(8))) short bf16x8;
typedef __attribute__((ext_vector_type(4))) float f32x4;

#define AS1(p) ((const __attribute__((address_space(1))) void*)(p))
#define AS3(p) ((__attribute__((address_space(3))) void*)(p))

__device__ __forceinline__ uint16_t f2bf(float f) {
  union { float f; uint32_t u; } v; v.f = f;
  uint32_t r = v.u + 0x7fffu + ((v.u >> 16) & 1u);
  return (uint16_t)(r >> 16);
}

// ---- weight packing: B_l[j][k] (128 x 256) bf16; k<128 -> W_rel, k>=128 -> W_root (layer1 zero-padded)
__global__ void pack_weights(const float* __restrict__ W1r, const float* __restrict__ W1o,
                             const float* __restrict__ W2r, const float* __restrict__ W2o,
                             const float* __restrict__ W3r, const float* __restrict__ W3o,
                             uint16_t* __restrict__ B1, uint16_t* __restrict__ B2, uint16_t* __restrict__ B3) {
  int idx = blockIdx.x * 256 + threadIdx.x;      // < 3*128*256
  int l = idx >> 15;
  int rem = idx & 32767;
  int j = rem >> 8;
  int k = rem & 255;
  if (l == 0) {
    uint16_t v = 0;
    if (k < FIN) v = f2bf(W1r[j*FIN + k]);
    else if (k >= 128 && k < 128 + FIN) v = f2bf(W1o[j*FIN + (k - 128)]);
    B1[j*256 + k] = v;
  } else if (l == 1) {
    B2[j*256 + k] = (k < 128) ? f2bf(W2r[j*128 + k]) : f2bf(W2o[j*128 + (k - 128)]);
  } else {
    B3[j*256 + k] = (k < 128) ? f2bf(W3r[j*128 + k]) : f2bf(W3o[j*128 + (k - 128)]);
  }
}

// ---- W_lin [47,384] f32 -> Wlb [48,384] bf16 (row 47 zero)
__global__ void pack_wl(const float* __restrict__ Wl, uint16_t* __restrict__ Wlb) {
  int idx = blockIdx.x * 256 + threadIdx.x;      // < 48*384
  int r = idx / 384;
  int c = idx - r * 384;
  Wlb[idx] = (r < CLS) ? f2bf(Wl[r*384 + c]) : (uint16_t)0;
}

// ---- pad+convert x0 [N,100] f32 -> x0p [N,128] bf16 (zeros in cols 100..127); 4 nodes/block
__global__ __launch_bounds__(256) void pad_x0(const float* __restrict__ x0, uint16_t* __restrict__ x0p) {
  int n = blockIdx.x * 4 + (threadIdx.x >> 6);
  int c = 2 * (threadIdx.x & 63);
  uint32_t o = 0;
  if (c < FIN) {
    float2 v = *(const float2*)(x0 + (size_t)n*FIN + c);
    o = ((uint32_t)f2bf(v.y) << 16) | (uint32_t)f2bf(v.x);
  }
  *(uint32_t*)(x0p + (size_t)n*HID + c) = o;
}

// ======== binned CSR build (write-coalescing-aware) ========
// Stage 1: per-bucket counts via LDS pre-aggregation (196 blocks x 8192-edge tiles)
__global__ __launch_bounds__(512) void bucket_hist(const int* __restrict__ dst, int* __restrict__ bcnt) {
  __shared__ int h[NBUK];
  int tid = threadIdx.x;
  for (int i = tid; i < NBUK; i += 512) h[i] = 0;
  __syncthreads();
  int tile0 = blockIdx.x * 8192;
  int n = NE - tile0; if (n > 8192) n = 8192;
  for (int i = tid; i < n; i += 512) atomicAdd(&h[dst[tile0 + i] >> 8], 1);
  __syncthreads();
  for (int i = tid; i < NBUK; i += 512) if (h[i]) atomicAdd(&bcnt[i], h[i]);
}

// Stage 2: exclusive scan of 391 bucket counts -> bases (fill = working copy)
__global__ __launch_bounds__(512) void bucket_scan(const int* __restrict__ bcnt,
                                                   int* __restrict__ bfill, int* __restrict__ bbase) {
  __shared__ int sh[512];
  int t = threadIdx.x;
  int v = (t < NBUK) ? bcnt[t] : 0;
  sh[t] = v;
  __syncthreads();
  for (int off = 1; off < 512; off <<= 1) {
    int tv = (t >= off) ? sh[t - off] : 0;
    __syncthreads();
    sh[t] += tv;
    __syncthreads();
  }
  if (t < NBUK) {
    int e = sh[t] - v;
    bfill[t] = e;
    bbase[t] = e;
  }
  if (t == 0) bbase[NBUK] = NE;
}

// Stage 3: binned scatter. Each block claims contiguous per-bucket chunks so all
// writes to a chunk come from ONE CU -> L2 write-combining -> full-line writebacks.
// Packed rec: x = src | dstLocal<<17 (src<2^17, dstLocal<256), y = weight bits.
__global__ __launch_bounds__(512) void binscat(const int* __restrict__ src, const int* __restrict__ dst,
                                               const float* __restrict__ ew,
                                               int* __restrict__ bfill, int2* __restrict__ ebin) {
  __shared__ int h[NBUK];
  __shared__ int base[NBUK];
  int tid = threadIdx.x;
  for (int i = tid; i < NBUK; i += 512) h[i] = 0;
  __syncthreads();
  int tile0 = blockIdx.x * 8192;
  int n = NE - tile0; if (n > 8192) n = 8192;
  for (int i = tid; i < n; i += 512) atomicAdd(&h[dst[tile0 + i] >> 8], 1);
  __syncthreads();
  for (int i = tid; i < NBUK; i += 512) base[i] = h[i] ? atomicAdd(&bfill[i], h[i]) : 0;
  __syncthreads();
  for (int i = tid; i < NBUK; i += 512) h[i] = 0;
  __syncthreads();
  for (int i = tid; i < n; i += 512) {
    int e = tile0 + i;
    int d = dst[e];
    int b = d >> 8;
    int r = atomicAdd(&h[b], 1);
    ebin[base[b] + r] = make_int2(src[e] | ((d & 255) << 17), __float_as_int(ew[e]));
  }
}

// Stage 4: one block per bucket. LDS hist+scan over the 256 local nodes gives
// row_start directly (replaces the old 4-kernel global scan), then scatters the
// final erec {src byte-offset, weight} within this bucket's ~33KB window —
// single CU => coalesced full-line writebacks.
__global__ __launch_bounds__(256) void bucket_csr(const int2* __restrict__ ebin,
                                                  const int* __restrict__ bbase,
                                                  int* __restrict__ row_start,
                                                  int2* __restrict__ erec) {
  __shared__ int sh[256];
  __shared__ int fill[256];
  int b = blockIdx.x;
  int tid = threadIdx.x;
  int ebase = bbase[b], eend = bbase[b + 1];
  int cnt = eend - ebase;
  sh[tid] = 0;
  __syncthreads();
  for (int i = tid; i < cnt; i += 256) atomicAdd(&sh[(uint32_t)ebin[ebase + i].x >> 17], 1);
  __syncthreads();
  int histv = sh[tid];
  __syncthreads();
  for (int off = 1; off < 256; off <<= 1) {
    int tv = (tid >= off) ? sh[tid - off] : 0;
    __syncthreads();
    sh[tid] += tv;
    __syncthreads();
  }
  int excl = sh[tid] - histv;
  int node = b * 256 + tid;
  if (node <= NN) row_start[node] = ebase + excl;   // node==NN -> ebase+cnt == NE
  fill[tid] = ebase + excl;
  __syncthreads();
  for (int i = tid; i < cnt; i += 256) {
    int2 rec = ebin[ebase + i];
    int dl = (uint32_t)rec.x >> 17;
    int s = rec.x & 0x1FFFF;
    int pos = atomicAdd(&fill[dl], 1);
    erec[pos] = make_int2(s << 8, rec.y);           // s*256 = byte offset (HID*2 per row)
  }
}

// ---- SpMM: agg[n,:] = sum_{e in row n} w_e * x[src_e,:]
// one wave per node, lane = 2 cols; predicated batches of 8 (out-of-range lanes
// clamp the index and zero the weight -> no serial tail, gather count near-minimal)
__global__ __launch_bounds__(256) void spmm_kernel(const uint16_t* __restrict__ x,
                                                   const int* __restrict__ row_start,
                                                   const int2* __restrict__ erec,
                                                   uint16_t* __restrict__ agg) {
  int n = blockIdx.x * 4 + (threadIdx.x >> 6);
  int l = threadIdx.x & 63;
  int s0 = row_start[n], s1 = row_start[n + 1];
  const char* xb = (const char*)x;
  int loff = 4 * l;
  float a0 = 0.f, a1 = 0.f;
  for (int e = s0; e < s1; e += 8) {
    int2 r[8];
    #pragma unroll
    for (int u = 0; u < 8; ++u) {
      int ee = e + u;
      r[u] = erec[ee < s1 ? ee : s1 - 1];
    }
    uint32_t pair[8];
    #pragma unroll
    for (int u = 0; u < 8; ++u)
      pair[u] = *(const uint32_t*)(xb + (size_t)(uint32_t)r[u].x + loff);
    #pragma unroll
    for (int u = 0; u < 8; ++u) {
      float w = (e + u < s1) ? __int_as_float(r[u].y) : 0.f;
      union { uint32_t u32; float f; } lo, hi;
      lo.u32 = pair[u] << 16; hi.u32 = pair[u] & 0xffff0000u;
      a0 += w * lo.f;
      a1 += w * hi.f;
    }
  }
  uint32_t o = ((uint32_t)f2bf(a1) << 16) | (uint32_t)f2bf(a0);
  *(uint32_t*)(agg + (size_t)n*HID + 2*l) = o;
}

// ---- fused GEMM: out = relu([A1|A2] @ B^T + bias), A1/A2 [N,128] bf16, B [128 x 256] bf16 (j-major), bias f32
__global__ __launch_bounds__(256) void gemm_kernel(const uint16_t* __restrict__ A1, const uint16_t* __restrict__ A2,
                                                   const uint16_t* __restrict__ Bm, const float* __restrict__ bias,
                                                   uint16_t* __restrict__ out) {
  __shared__ uint16_t ldsA[128 * 32];
  __shared__ uint16_t ldsB[128 * 32];
  int t = threadIdx.x;
  int n0 = blockIdx.x * 128;
  int lane = t & 63, wave = t >> 6;
  int wm = (wave >> 1) * 64, wn = (wave & 1) * 64;
  int l15 = lane & 15, quad = lane >> 4;

  f32x4 acc[4][4];
  #pragma unroll
  for (int i = 0; i < 4; ++i)
    #pragma unroll
    for (int j = 0; j < 4; ++j) acc[i][j] = (f32x4){0.f, 0.f, 0.f, 0.f};

  for (int kt = 0; kt < 8; ++kt) {
    int kbase = kt * 32;
    const uint16_t* Asrc = (kbase < 128) ? A1 : A2;
    int klocal = kbase & 127;
    #pragma unroll
    for (int q = 0; q < 2; ++q) {
      int u = t + q * 256;                 // 0..511
      int r = u >> 2;                      // 0..127
      int kg = (u & 3) * 8;
      int rowA = n0 + r; if (rowA >= NN) rowA = NN - 1;
      __builtin_amdgcn_global_load_lds(AS1(Asrc + (size_t)rowA*HID + klocal + kg), AS3(&ldsA[u * 8]), 16, 0, 0);
      __builtin_amdgcn_global_load_lds(AS1(Bm + r*256 + kbase + kg), AS3(&ldsB[u * 8]), 16, 0, 0);
    }
    __syncthreads();
    bf16x8 af[4], bfr[4];
    #pragma unroll
    for (int mi = 0; mi < 4; ++mi) af[mi] = *(const bf16x8*)&ldsA[(wm + mi*16 + l15) * 32 + quad * 8];
    #pragma unroll
    for (int ni = 0; ni < 4; ++ni) bfr[ni] = *(const bf16x8*)&ldsB[(wn + ni*16 + l15) * 32 + quad * 8];
    #pragma unroll
    for (int mi = 0; mi < 4; ++mi)
      #pragma unroll
      for (int ni = 0; ni < 4; ++ni)
        acc[mi][ni] = __builtin_amdgcn_mfma_f32_16x16x32_bf16(af[mi], bfr[ni], acc[mi][ni], 0, 0, 0);
    __syncthreads();
  }

  #pragma unroll
  for (int mi = 0; mi < 4; ++mi) {
    #pragma unroll
    for (int ni = 0; ni < 4; ++ni) {
      int c = wn + ni*16 + l15;
      float bc = bias[c];
      #pragma unroll
      for (int i = 0; i < 4; ++i) {
        int r = n0 + wm + mi*16 + quad*4 + i;
        if (r < NN) {
          float v = acc[mi][ni][i] + bc;
          v = v > 0.f ? v : 0.f;
          out[(size_t)r*HID + c] = f2bf(v);
        }
      }
    }
  }
}

// ---- final: logits = [x1|x2|x3] @ Wlb^T + bl ; log_softmax ; store f32
__global__ __launch_bounds__(256) void final_kernel(const uint16_t* __restrict__ x1, const uint16_t* __restrict__ x2,
                                                    const uint16_t* __restrict__ x3,
                                                    const uint16_t* __restrict__ Wlb, const float* __restrict__ bl,
                                                    float* __restrict__ out) {
  int t = threadIdx.x;
  int lane = t & 63, wave = t >> 6;
  int n0 = blockIdx.x * 64 + wave * 16;
  int l15 = lane & 15, quad = lane >> 4;

  f32x4 acc[3];
  #pragma unroll
  for (int i = 0; i < 3; ++i) acc[i] = (f32x4){0.f, 0.f, 0.f, 0.f};

  int arow = n0 + l15; if (arow >= NN) arow = NN - 1;

  #pragma unroll
  for (int kt = 0; kt < 12; ++kt) {
    const uint16_t* xs = (kt < 4) ? x1 : (kt < 8) ? x2 : x3;
    int klocal = (kt & 3) * 32 + quad * 8;
    bf16x8 af = *(const bf16x8*)(xs + (size_t)arow*HID + klocal);
    int kglob = kt * 32 + quad * 8;
    #pragma unroll
    for (int nt = 0; nt < 3; ++nt) {
      int c = nt*16 + l15;                 // < 48, row 47 of Wlb is zero
      bf16x8 bfr = *(const bf16x8*)(Wlb + (size_t)c*(3*HID) + kglob);
      acc[nt] = __builtin_amdgcn_mfma_f32_16x16x32_bf16(af, bfr, acc[nt], 0, 0, 0);
    }
  }

  float bias[3]; bool valid[3];
  #pragma unroll
  for (int nt = 0; nt < 3; ++nt) {
    int c = nt*16 + l15;
    valid[nt] = (c < CLS);
    bias[nt] = valid[nt] ? bl[c] : 0.f;
  }

  #pragma unroll
  for (int i = 0; i < 4; ++i) {
    int r = n0 + quad*4 + i;
    float v0 = acc[0][i] + bias[0];
    float v1 = acc[1][i] + bias[1];
    float v2 = valid[2] ? (acc[2][i] + bias[2]) : -INFINITY;
    float m = fmaxf(v0, fmaxf(v1, v2));
    #pragma unroll
    for (int off = 8; off >= 1; off >>= 1) m = fmaxf(m, __shfl_xor(m, off, 64));
    float s = __expf(v0 - m) + __expf(v1 - m) + (valid[2] ? __expf(v2 - m) : 0.f);
    #pragma unroll
    for (int off = 8; off >= 1; off >>= 1) s += __shfl_xor(s, off, 64);
    float lse = m + __logf(s);
    if (r < NN) {
      out[(size_t)r*CLS + l15]      = v0 - lse;
      out[(size_t)r*CLS + 16 + l15] = v1 - lse;
      if (valid[2]) out[(size_t)r*CLS + 32 + l15] = v2 - lse;
    }
  }
}

extern "C" void kernel_launch(void* const* d_in, const int* in_sizes, int n_in,
                              void* d_out, int out_size, void* d_ws, size_t ws_size,
                              hipStream_t stream) {
  (void)in_sizes; (void)n_in; (void)out_size; (void)ws_size;
  const float* x0  = (const float*)d_in[0];
  const int*   ei  = (const int*)d_in[1];
  const float* ew  = (const float*)d_in[2];
  const float* W1r = (const float*)d_in[3];
  const float* W1o = (const float*)d_in[4];
  const float* b1  = (const float*)d_in[5];
  const float* W2r = (const float*)d_in[6];
  const float* W2o = (const float*)d_in[7];
  const float* b2  = (const float*)d_in[8];
  const float* W3r = (const float*)d_in[9];
  const float* W3o = (const float*)d_in[10];
  const float* b3  = (const float*)d_in[11];
  const float* Wl  = (const float*)d_in[12];
  const float* bl  = (const float*)d_in[13];
  const int* src = ei;
  const int* dst = ei + NE;

  char* ws = (char*)d_ws;
  size_t off = 0;
  auto alloc = [&](size_t bytes) -> void* {
    void* p = ws + off;
    off += (bytes + 255) & ~(size_t)255;
    return p;
  };
  uint16_t* x0p = (uint16_t*)alloc((size_t)NN * HID * 2);   // also reused as xb2
  uint16_t* xb1 = (uint16_t*)alloc((size_t)NN * HID * 2);
  uint16_t* xb3 = (uint16_t*)alloc((size_t)NN * HID * 2);
  uint16_t* agg = (uint16_t*)alloc((size_t)NN * HID * 2);
  int2*   erec      = (int2*)alloc((size_t)NE * 8);
  int2*   ebin      = (int2*)alloc((size_t)NE * 8);
  int*    row_start = (int*)alloc((size_t)(NN + 1) * 4);
  int*    bcnt      = (int*)alloc(NBUK * 4);
  int*    bfill     = (int*)alloc(NBUK * 4);
  int*    bbase     = (int*)alloc((NBUK + 1) * 4);
  uint16_t* B1 = (uint16_t*)alloc(128 * 256 * 2);
  uint16_t* B2 = (uint16_t*)alloc(128 * 256 * 2);
  uint16_t* B3 = (uint16_t*)alloc(128 * 256 * 2);
  uint16_t* Wlb = (uint16_t*)alloc(48 * 384 * 2);
  uint16_t* xb2 = x0p;   // alias: x0p dead after layer-1 GEMM

  const int TB = (NE + 8191) / 8192;      // 196 tiles

  hipMemsetAsync(bcnt, 0, NBUK * 4, stream);
  pack_weights<<<384, 256, 0, stream>>>(W1r, W1o, W2r, W2o, W3r, W3o, B1, B2, B3);
  pack_wl<<<72, 256, 0, stream>>>(Wl, Wlb);
  pad_x0<<<NN / 4, 256, 0, stream>>>(x0, x0p);
  bucket_hist<<<TB, 512, 0, stream>>>(dst, bcnt);
  bucket_scan<<<1, 512, 0, stream>>>(bcnt, bfill, bbase);
  binscat<<<TB, 512, 0, stream>>>(src, dst, ew, bfill, ebin);
  bucket_csr<<<NBUK, 256, 0, stream>>>(ebin, bbase, row_start, erec);

  spmm_kernel<<<NN / 4, 256, 0, stream>>>(x0p, row_start, erec, agg);
  gemm_kernel<<<(NN + 127) / 128, 256, 0, stream>>>(agg, x0p, B1, b1, xb1);
  spmm_kernel<<<NN / 4, 256, 0, stream>>>(xb1, row_start, erec, agg);
  gemm_kernel<<<(NN + 127) / 128, 256, 0, stream>>>(agg, xb1, B2, b2, xb2);
  spmm_kernel<<<NN / 4, 256, 0, stream>>>(xb2, row_start, erec, agg);
  gemm_kernel<<<(NN + 127) / 128, 256, 0, stream>>>(agg, xb2, B3, b3, xb3);

  final_kernel<<<(NN + 63) / 64, 256, 0, stream>>>(xb1, xb2, xb3, Wlb, bl, (float*)d_out);
}